// Round 6
// baseline (803.448 us; speedup 1.0000x reference)
//
#include <hip/hip_runtime.h>
#include <hip/hip_bf16.h>
#include <cstdint>
#include <cstddef>

// ---------- types ----------
typedef short bf16x8 __attribute__((ext_vector_type(8)));     // 8 bf16 in 4 VGPRs
typedef float f32x4 __attribute__((ext_vector_type(4)));
typedef float f32x16 __attribute__((ext_vector_type(16)));
typedef unsigned short u16x4 __attribute__((ext_vector_type(4)));

__device__ __forceinline__ unsigned short f2bf(float f) {
  unsigned int u = __builtin_bit_cast(unsigned int, f);
  u = (u + 0x7FFFu + ((u >> 16) & 1u)) >> 16;   // RNE
  return (unsigned short)u;
}

__device__ __forceinline__ f32x4 mfma16x16x32(bf16x8 a, bf16x8 b, f32x4 c) {
  return __builtin_amdgcn_mfma_f32_16x16x32_bf16(a, b, c, 0, 0, 0);
}
__device__ __forceinline__ f32x16 mfma32x32x16(bf16x8 a, bf16x8 b, f32x16 c) {
  return __builtin_amdgcn_mfma_f32_32x32x16_bf16(a, b, c, 0, 0, 0);
}

// padded strides (elements) to break L1 set-aliasing (4KB way size):
constexpr int KSTRIDE = 1056;   // K rows: 2112 B (2048+64)
constexpr int VSTRIDE = 2080;   // V^T rows: 4160 B (4096+64)

// ---------- f32 -> bf16 conversion ----------
__global__ __launch_bounds__(256) void cvt_f32_bf16(const float* __restrict__ src,
                                                    unsigned short* __restrict__ dst, int n) {
  int i = (blockIdx.x * 256 + threadIdx.x) * 4;
  if (i + 3 < n) {
    float4 v = *reinterpret_cast<const float4*>(src + i);
    u16x4 o;
    o[0] = f2bf(v.x); o[1] = f2bf(v.y); o[2] = f2bf(v.z); o[3] = f2bf(v.w);
    *reinterpret_cast<u16x4*>(dst + i) = o;
  }
}

// ---------- GEMM: C[M,N] = A[M,K] * Bw[N,K]^T  (bf16 in, f32 accum) ----------
// OUTMODE: 0 = bf16 row-major stride N
//          1 = f32 row-major stride N
//          2 = bf16 V-transposed PADDED: out[((row>>11)*1024 + col)*VSTRIDE + (row&2047)]
//          3 = bf16 row-major, values * 0.125 (Q projection, folds attn scale)
//          4 = bf16 row-major PADDED stride KSTRIDE (K projection)
template <int OUTMODE>
__global__ __launch_bounds__(256) void gemm_bt(const unsigned short* __restrict__ A,
                                               const unsigned short* __restrict__ Bw,
                                               void* __restrict__ Cp,
                                               int M, int N, int K) {
  __shared__ unsigned short As[128 * 32];
  __shared__ unsigned short Bs[128 * 32];
  const int tid  = threadIdx.x;
  const int lane = tid & 63, wid = tid >> 6;
  const int g = lane >> 4, cc = lane & 15;
  const int wr = wid >> 1, wc = wid & 1;
  const int m0 = blockIdx.y * 128, n0 = blockIdx.x * 128;
  const int arow = tid >> 2;          // 0..63
  const int acol = (tid & 3) * 8;     // 0,8,16,24

  const unsigned short* gA = A  + (size_t)(m0 + arow) * K + acol;
  const unsigned short* gB = Bw + (size_t)(n0 + arow) * K + acol;

  f32x4 acc[4][4];
#pragma unroll
  for (int i = 0; i < 4; ++i)
#pragma unroll
    for (int j = 0; j < 4; ++j) acc[i][j] = f32x4{0.f, 0.f, 0.f, 0.f};

  for (int k0 = 0; k0 < K; k0 += 32) {
    __builtin_amdgcn_global_load_lds(
        (const __attribute__((address_space(1))) void*)(gA + k0),
        (__attribute__((address_space(3))) void*)(As + wid * 512), 16, 0, 0);
    __builtin_amdgcn_global_load_lds(
        (const __attribute__((address_space(1))) void*)(gA + (size_t)64 * K + k0),
        (__attribute__((address_space(3))) void*)(As + 2048 + wid * 512), 16, 0, 0);
    __builtin_amdgcn_global_load_lds(
        (const __attribute__((address_space(1))) void*)(gB + k0),
        (__attribute__((address_space(3))) void*)(Bs + wid * 512), 16, 0, 0);
    __builtin_amdgcn_global_load_lds(
        (const __attribute__((address_space(1))) void*)(gB + (size_t)64 * K + k0),
        (__attribute__((address_space(3))) void*)(Bs + 2048 + wid * 512), 16, 0, 0);
    __syncthreads();

    bf16x8 af[4], bfv[4];
#pragma unroll
    for (int mi = 0; mi < 4; ++mi)
      af[mi] = *reinterpret_cast<const bf16x8*>(As + (wr * 64 + mi * 16 + cc) * 32 + g * 8);
#pragma unroll
    for (int ni = 0; ni < 4; ++ni)
      bfv[ni] = *reinterpret_cast<const bf16x8*>(Bs + (wc * 64 + ni * 16 + cc) * 32 + g * 8);
#pragma unroll
    for (int mi = 0; mi < 4; ++mi)
#pragma unroll
      for (int ni = 0; ni < 4; ++ni)
        acc[mi][ni] = mfma16x16x32(af[mi], bfv[ni], acc[mi][ni]);
    __syncthreads();
  }

  // epilogue: D row = (lane>>4)*4 + r, col = lane&15  (verified mapping)
#pragma unroll
  for (int mi = 0; mi < 4; ++mi) {
#pragma unroll
    for (int ni = 0; ni < 4; ++ni) {
      const int row0 = m0 + wr * 64 + mi * 16 + g * 4;
      const int col  = n0 + wc * 64 + ni * 16 + cc;
      if (OUTMODE == 2) {
        u16x4 o;
#pragma unroll
        for (int r = 0; r < 4; ++r) o[r] = f2bf(acc[mi][ni][r]);
        const size_t idx = ((size_t)(row0 >> 11) * 1024 + col) * VSTRIDE + (row0 & 2047);
        *reinterpret_cast<u16x4*>(reinterpret_cast<unsigned short*>(Cp) + idx) = o;
      } else {
#pragma unroll
        for (int r = 0; r < 4; ++r) {
          const int row = row0 + r;
          if (OUTMODE == 1)
            reinterpret_cast<float*>(Cp)[(size_t)row * N + col] = acc[mi][ni][r];
          else if (OUTMODE == 3)
            reinterpret_cast<unsigned short*>(Cp)[(size_t)row * N + col] = f2bf(acc[mi][ni][r] * 0.125f);
          else if (OUTMODE == 4)
            reinterpret_cast<unsigned short*>(Cp)[(size_t)row * KSTRIDE + col] = f2bf(acc[mi][ni][r]);
          else
            reinterpret_cast<unsigned short*>(Cp)[(size_t)row * N + col] = f2bf(acc[mi][ni][r]);
        }
      }
    }
  }
}

// ---------- causal flash attention, 32x32 MFMA, in-register softmax ----------
// Q: [B*S][1024] bf16, pre-scaled by 0.125 (col = h*64+d)
// K: [B*S][KSTRIDE] bf16 padded row-major
// Vt: per (b,h) a [64][VSTRIDE] tile: Vt[((b*16+h)*64 + d)*VSTRIDE + s]
// O: [B*S][1024] bf16
// 1 wave = 32 q-rows. QK^T computed as D[kv][q] = mfma(K-frag, Q-frag):
//   C/D 32x32 mapping: col = lane&31 (= q), row = (r&3)+8*(r>>2)+4*(lane>>5) (= kv_local)
//   -> lane holds P^T values for ONE q (its column) across 16 kv slots; partner (^32)
//      the other 16. Softmax state (m,l) is per-lane COLUMN state (q = lane&31).
//   PV accumulator rows are q_row = (i&3)+8*(i>>2)+4*hi — a DIFFERENT q per register:
//   every per-q correction applied to acc MUST be shuffled from lane q_row.
// A/B frag for 32x32x16: row/col = lane&31, k = (lane>>5)*8 + j.
__global__ __launch_bounds__(256) void attn_fwd(const unsigned short* __restrict__ Q,
                                                const unsigned short* __restrict__ Kp,
                                                const unsigned short* __restrict__ Vt,
                                                unsigned short* __restrict__ O) {
  constexpr int S = 2048, DM = 1024;
  const int tid  = threadIdx.x;
  const int lane = tid & 63, wid = tid >> 6;
  const int l31 = lane & 31, hi = lane >> 5;
  const int bq = blockIdx.x & 15;           // S/128
  const int h  = (blockIdx.x >> 4) & 15;
  const int b  = blockIdx.x >> 8;
  const int qw = bq * 128 + wid * 32;       // this wave's q-base

  const size_t baseQ = (size_t)b * S * DM + (size_t)h * 64;
  const size_t baseK = (size_t)b * S * KSTRIDE + (size_t)h * 64;
  const unsigned short* Vbh = Vt + (size_t)((b * 16 + h) * 64) * VSTRIDE;

  // hoist Q fragments (B-operand: lane holds Q[qw+l31][m*16 + hi*8 + j])
  const unsigned short* Qrow = Q + baseQ + (size_t)(qw + l31) * DM + hi * 8;
  bf16x8 qf[4];
#pragma unroll
  for (int m = 0; m < 4; ++m) qf[m] = *reinterpret_cast<const bf16x8*>(Qrow + m * 16);

  f32x16 acc0, acc1;
#pragma unroll
  for (int i = 0; i < 16; ++i) { acc0[i] = 0.f; acc1[i] = 0.f; }
  float m_st = -3.0e38f, l_st = 0.f;

  const unsigned short* Kr0 = Kp + baseK + (size_t)l31 * KSTRIDE + hi * 8;

  for (int kv0 = 0; kv0 <= qw; kv0 += 32) {
    // --- QK^T: D[kv][q], 4 K=16 slices over d=64 ---
    const unsigned short* Kr = Kr0 + (size_t)kv0 * KSTRIDE;
    f32x16 s;
#pragma unroll
    for (int i = 0; i < 16; ++i) s[i] = 0.f;
#pragma unroll
    for (int m = 0; m < 4; ++m)
      s = mfma32x32x16(*reinterpret_cast<const bf16x8*>(Kr + m * 16), qf[m], s);

    // --- causal mask: only the diagonal tile needs it ---
    float p[16];
    if (kv0 == qw) {
#pragma unroll
      for (int r = 0; r < 16; ++r) {
        const int kvl = (r & 3) + 8 * (r >> 2) + 4 * hi;
        p[r] = (kvl <= l31) ? s[r] : -3.0e38f;
      }
    } else {
#pragma unroll
      for (int r = 0; r < 16; ++r) p[r] = s[r];
    }

    // --- row max (per q = l31): in-lane tree + cross-half ---
    float tm = p[0];
#pragma unroll
    for (int r = 1; r < 16; ++r) tm = fmaxf(tm, p[r]);
    tm = fmaxf(tm, __shfl_xor(tm, 32));

    // --- online rescale (exact defer: skip when no lane's max grew) ---
    if (!__all(tm <= m_st)) {
      const float m_new = fmaxf(m_st, tm);
      const float corr  = __expf(m_st - m_new);   // per-lane, for q = l31
      // acc rows are q_row = (i&3)+8*(i>>2)+4*hi, NOT l31: fetch that q's corr
#pragma unroll
      for (int i = 0; i < 16; ++i) {
        const int qr = (i & 3) + 8 * (i >> 2) + 4 * hi;
        const float cr = __shfl(corr, qr);
        acc0[i] *= cr; acc1[i] *= cr;
      }
      l_st *= corr;
      m_st = m_new;
    }

    // --- P = exp(S - m), row sum ---
    float ls = 0.f;
#pragma unroll
    for (int r = 0; r < 16; ++r) { p[r] = __expf(p[r] - m_st); ls += p[r]; }
    ls += __shfl_xor(ls, 32);
    l_st += ls;

    // --- PV: two K=16 slices (ks), A-frag needs P[q][ks*16 + hi*8 + j] ---
#pragma unroll
    for (int ks = 0; ks < 2; ++ks) {
      const int bb = ks * 8;
      float u[4];
#pragma unroll
      for (int i = 0; i < 4; ++i) {
        const float t = hi ? p[bb + i] : p[bb + 4 + i];
        u[i] = __shfl_xor(t, 32);
      }
      bf16x8 pa;
#pragma unroll
      for (int j = 0; j < 4; ++j) {
        pa[j]     = (short)f2bf(hi ? u[j] : p[bb + j]);
        pa[4 + j] = (short)f2bf(hi ? p[bb + 4 + j] : u[j]);
      }
      const int vcol = kv0 + ks * 16 + hi * 8;
      acc0 = mfma32x32x16(pa, *reinterpret_cast<const bf16x8*>(Vbh + (size_t)l31 * VSTRIDE + vcol), acc0);
      acc1 = mfma32x32x16(pa, *reinterpret_cast<const bf16x8*>(Vbh + (size_t)(32 + l31) * VSTRIDE + vcol), acc1);
    }
  }

  // --- epilogue: normalize, store O (row qw+qr, cols dn*32 + l31) ---
  const float invl = 1.0f / l_st;
#pragma unroll
  for (int r = 0; r < 16; ++r) {
    const int qr = (r & 3) + 8 * (r >> 2) + 4 * hi;
    const float il = __shfl(invl, qr);
    unsigned short* Orow = O + baseQ + (size_t)(qw + qr) * DM;
    Orow[l31]      = f2bf(acc0[r] * il);
    Orow[32 + l31] = f2bf(acc1[r] * il);
  }
}

// ---------- launch ----------
extern "C" void kernel_launch(void* const* d_in, const int* in_sizes, int n_in,
                              void* d_out, int out_size, void* d_ws, size_t ws_size,
                              hipStream_t stream) {
  (void)in_sizes; (void)n_in; (void)out_size; (void)ws_size;
  constexpr int Bx = 4, S = 2048, DM = 1024;
  constexpr int M = Bx * S;          // 8192
  constexpr size_t XEL = (size_t)M * DM;       // 8388608
  constexpr size_t WEL = (size_t)DM * DM;      // 1048576

  const float* Wq = (const float*)d_in[1];
  const float* Wk = (const float*)d_in[2];
  const float* Wv = (const float*)d_in[3];
  const float* Wo = (const float*)d_in[4];
  const float* Xf = (const float*)d_in[5];
  float* out = (float*)d_out;

  char* ws = (char*)d_ws;
  unsigned short* Xbf = (unsigned short*)(ws + 0);           // 16 MB (reused as attn-out)
  unsigned short* Qb  = (unsigned short*)(ws + 16777216);    // [8192][1024]
  unsigned short* Kb  = (unsigned short*)(ws + 33554432);    // [8192][1056] padded
  unsigned short* Vtb = (unsigned short*)(ws + 50855936);    // [4096][2080] padded V^T
  unsigned short* Wqb = (unsigned short*)(ws + 67895296);
  unsigned short* Wkb = (unsigned short*)(ws + 69992448);
  unsigned short* Wvb = (unsigned short*)(ws + 72089600);
  unsigned short* Wob = (unsigned short*)(ws + 74186752);
  unsigned short* Ob  = Xbf;   // alias: X dead after V projection

  // 1) convert inputs to bf16
  cvt_f32_bf16<<<(int)(XEL / 1024), 256, 0, stream>>>(Xf, Xbf, (int)XEL);
  cvt_f32_bf16<<<(int)(WEL / 1024), 256, 0, stream>>>(Wq, Wqb, (int)WEL);
  cvt_f32_bf16<<<(int)(WEL / 1024), 256, 0, stream>>>(Wk, Wkb, (int)WEL);
  cvt_f32_bf16<<<(int)(WEL / 1024), 256, 0, stream>>>(Wv, Wvb, (int)WEL);
  cvt_f32_bf16<<<(int)(WEL / 1024), 256, 0, stream>>>(Wo, Wob, (int)WEL);

  // 2) projections: Q (scaled 1/8), K (padded rows), V (transposed+padded)
  dim3 gg(DM / 128, M / 128);   // (8, 64)
  gemm_bt<3><<<gg, 256, 0, stream>>>(Xbf, Wqb, Qb, M, DM, DM);
  gemm_bt<4><<<gg, 256, 0, stream>>>(Xbf, Wkb, Kb, M, DM, DM);
  gemm_bt<2><<<gg, 256, 0, stream>>>(Xbf, Wvb, Vtb, M, DM, DM);

  // 3) causal flash attention (writes Ob, aliasing Xbf)
  attn_fwd<<<Bx * 16 * (S / 128), 256, 0, stream>>>(Qb, Kb, Vtb, Ob);

  // 4) output projection (f32 out)
  gemm_bt<1><<<gg, 256, 0, stream>>>(Ob, Wob, out, M, DM, DM);
}

// Round 7
// 415.697 us; speedup vs baseline: 1.9328x; 1.9328x over previous
//
#include <hip/hip_runtime.h>
#include <hip/hip_bf16.h>
#include <cstdint>
#include <cstddef>

// ---------- types ----------
typedef short bf16x8 __attribute__((ext_vector_type(8)));     // 8 bf16 in 4 VGPRs
typedef float f32x4 __attribute__((ext_vector_type(4)));
typedef float f32x16 __attribute__((ext_vector_type(16)));
typedef unsigned short u16x4 __attribute__((ext_vector_type(4)));

__device__ __forceinline__ unsigned short f2bf(float f) {
  unsigned int u = __builtin_bit_cast(unsigned int, f);
  u = (u + 0x7FFFu + ((u >> 16) & 1u)) >> 16;   // RNE
  return (unsigned short)u;
}

__device__ __forceinline__ f32x4 mfma16x16x32(bf16x8 a, bf16x8 b, f32x4 c) {
  return __builtin_amdgcn_mfma_f32_16x16x32_bf16(a, b, c, 0, 0, 0);
}
__device__ __forceinline__ f32x16 mfma32x32x16(bf16x8 a, bf16x8 b, f32x16 c) {
  return __builtin_amdgcn_mfma_f32_32x32x16_bf16(a, b, c, 0, 0, 0);
}

// padded strides (elements); keep from r4 (harmless for staging, 16B-aligned)
constexpr int KSTRIDE = 1056;   // K rows: 2112 B
constexpr int VSTRIDE = 2080;   // V^T rows: 4160 B

// ---------- f32 -> bf16 conversion ----------
__global__ __launch_bounds__(256) void cvt_f32_bf16(const float* __restrict__ src,
                                                    unsigned short* __restrict__ dst, int n) {
  int i = (blockIdx.x * 256 + threadIdx.x) * 4;
  if (i + 3 < n) {
    float4 v = *reinterpret_cast<const float4*>(src + i);
    u16x4 o;
    o[0] = f2bf(v.x); o[1] = f2bf(v.y); o[2] = f2bf(v.z); o[3] = f2bf(v.w);
    *reinterpret_cast<u16x4*>(dst + i) = o;
  }
}

// ---------- GEMM: C[M,N] = A[M,K] * Bw[N,K]^T  (bf16 in, f32 accum) ----------
// OUTMODE: 0 = bf16 row-major stride N
//          1 = f32 row-major stride N
//          2 = bf16 V-transposed PADDED: out[((row>>11)*1024 + col)*VSTRIDE + (row&2047)]
//          3 = bf16 row-major, values * 0.125 (Q projection, folds attn scale)
//          4 = bf16 row-major PADDED stride KSTRIDE (K projection)
template <int OUTMODE>
__global__ __launch_bounds__(256) void gemm_bt(const unsigned short* __restrict__ A,
                                               const unsigned short* __restrict__ Bw,
                                               void* __restrict__ Cp,
                                               int M, int N, int K) {
  __shared__ unsigned short As[128 * 32];
  __shared__ unsigned short Bs[128 * 32];
  const int tid  = threadIdx.x;
  const int lane = tid & 63, wid = tid >> 6;
  const int g = lane >> 4, cc = lane & 15;
  const int wr = wid >> 1, wc = wid & 1;
  const int m0 = blockIdx.y * 128, n0 = blockIdx.x * 128;
  const int arow = tid >> 2;          // 0..63
  const int acol = (tid & 3) * 8;     // 0,8,16,24

  const unsigned short* gA = A  + (size_t)(m0 + arow) * K + acol;
  const unsigned short* gB = Bw + (size_t)(n0 + arow) * K + acol;

  f32x4 acc[4][4];
#pragma unroll
  for (int i = 0; i < 4; ++i)
#pragma unroll
    for (int j = 0; j < 4; ++j) acc[i][j] = f32x4{0.f, 0.f, 0.f, 0.f};

  for (int k0 = 0; k0 < K; k0 += 32) {
    __builtin_amdgcn_global_load_lds(
        (const __attribute__((address_space(1))) void*)(gA + k0),
        (__attribute__((address_space(3))) void*)(As + wid * 512), 16, 0, 0);
    __builtin_amdgcn_global_load_lds(
        (const __attribute__((address_space(1))) void*)(gA + (size_t)64 * K + k0),
        (__attribute__((address_space(3))) void*)(As + 2048 + wid * 512), 16, 0, 0);
    __builtin_amdgcn_global_load_lds(
        (const __attribute__((address_space(1))) void*)(gB + k0),
        (__attribute__((address_space(3))) void*)(Bs + wid * 512), 16, 0, 0);
    __builtin_amdgcn_global_load_lds(
        (const __attribute__((address_space(1))) void*)(gB + (size_t)64 * K + k0),
        (__attribute__((address_space(3))) void*)(Bs + 2048 + wid * 512), 16, 0, 0);
    __syncthreads();

    bf16x8 af[4], bfv[4];
#pragma unroll
    for (int mi = 0; mi < 4; ++mi)
      af[mi] = *reinterpret_cast<const bf16x8*>(As + (wr * 64 + mi * 16 + cc) * 32 + g * 8);
#pragma unroll
    for (int ni = 0; ni < 4; ++ni)
      bfv[ni] = *reinterpret_cast<const bf16x8*>(Bs + (wc * 64 + ni * 16 + cc) * 32 + g * 8);
#pragma unroll
    for (int mi = 0; mi < 4; ++mi)
#pragma unroll
      for (int ni = 0; ni < 4; ++ni)
        acc[mi][ni] = mfma16x16x32(af[mi], bfv[ni], acc[mi][ni]);
    __syncthreads();
  }

  // epilogue: D row = (lane>>4)*4 + r, col = lane&15  (verified mapping)
#pragma unroll
  for (int mi = 0; mi < 4; ++mi) {
#pragma unroll
    for (int ni = 0; ni < 4; ++ni) {
      const int row0 = m0 + wr * 64 + mi * 16 + g * 4;
      const int col  = n0 + wc * 64 + ni * 16 + cc;
      if (OUTMODE == 2) {
        u16x4 o;
#pragma unroll
        for (int r = 0; r < 4; ++r) o[r] = f2bf(acc[mi][ni][r]);
        const size_t idx = ((size_t)(row0 >> 11) * 1024 + col) * VSTRIDE + (row0 & 2047);
        *reinterpret_cast<u16x4*>(reinterpret_cast<unsigned short*>(Cp) + idx) = o;
      } else {
#pragma unroll
        for (int r = 0; r < 4; ++r) {
          const int row = row0 + r;
          if (OUTMODE == 1)
            reinterpret_cast<float*>(Cp)[(size_t)row * N + col] = acc[mi][ni][r];
          else if (OUTMODE == 3)
            reinterpret_cast<unsigned short*>(Cp)[(size_t)row * N + col] = f2bf(acc[mi][ni][r] * 0.125f);
          else if (OUTMODE == 4)
            reinterpret_cast<unsigned short*>(Cp)[(size_t)row * KSTRIDE + col] = f2bf(acc[mi][ni][r]);
          else
            reinterpret_cast<unsigned short*>(Cp)[(size_t)row * N + col] = f2bf(acc[mi][ni][r]);
        }
      }
    }
  }
}

// ---------- causal flash attention, 32x32 MFMA, cooperative LDS staging ----------
// Q: [B*S][1024] bf16, pre-scaled by 0.125 (col = h*64+d)
// K: [B*S][KSTRIDE] bf16 padded row-major
// Vt: per (b,h) a [64][VSTRIDE] tile: Vt[((b*16+h)*64 + d)*VSTRIDE + s]
// O: [B*S][1024] bf16
//
// Block = 4 waves, one (b,h), q-rows [bq*128, bq*128+128); wave w owns 32 rows.
// Per 64-kv tile: block stages K-tile [64 kv][64 d] and V-tile [64 d][64 s] in LDS
// (global_load_lds w16; LDS dest LINEAR, global src pre-swizzled chunk ^= row&7,
//  reads use the same XOR — rule #21 both-sides swizzle). Each 128B LDS row spans
// all 32 banks; swizzle spreads the column-read to 8 chunk slots (residual 4-way).
//
// Math identical to r6 (verified): D[kv][q] = mfma(K,Q); lane's softmax state is for
// q = lane&31 (column); acc rows are q_row=(i&3)+8*(i>>2)+4*hi -> per-q corrections
// shuffled from lane q_row.
__global__ __launch_bounds__(256) void attn_fwd(const unsigned short* __restrict__ Q,
                                                const unsigned short* __restrict__ Kp,
                                                const unsigned short* __restrict__ Vt,
                                                unsigned short* __restrict__ O) {
  constexpr int S = 2048, DM = 1024;
  __shared__ unsigned short Kl[64 * 64];   // [kv][d] 8KB
  __shared__ unsigned short Vl[64 * 64];   // [d][s]  8KB
  const int tid  = threadIdx.x;
  const int lane = tid & 63, wid = tid >> 6;
  const int l31 = lane & 31, hi = lane >> 5;
  const int bq = blockIdx.x & 15;           // S/128
  const int h  = (blockIdx.x >> 4) & 15;
  const int b  = blockIdx.x >> 8;
  const int qw = bq * 128 + wid * 32;       // this wave's q-base

  const size_t baseQ = (size_t)b * S * DM + (size_t)h * 64;
  const unsigned short* Kbh = Kp + (size_t)b * S * KSTRIDE + (size_t)h * 64;
  const unsigned short* Vbh = Vt + (size_t)((b * 16 + h) * 64) * VSTRIDE;

  // hoist Q fragments (B-operand: lane holds Q[qw+l31][m*16 + hi*8 + j])
  const unsigned short* Qrow = Q + baseQ + (size_t)(qw + l31) * DM + hi * 8;
  bf16x8 qf[4];
#pragma unroll
  for (int m = 0; m < 4; ++m) qf[m] = *reinterpret_cast<const bf16x8*>(Qrow + m * 16);

  f32x16 acc0, acc1;
#pragma unroll
  for (int i = 0; i < 16; ++i) { acc0[i] = 0.f; acc1[i] = 0.f; }
  float m_st = -3.0e38f, l_st = 0.f;

  // staging coords: thread covers row r0 (call0) / r0+32 (call1), chunk sc (16B)
  const int r0 = wid * 8 + (lane >> 3);
  const int sc = lane & 7;
  const int c0 = (sc ^ (r0 & 7)) * 8;            // pre-swizzled source chunk (elements)
  const int c1 = (sc ^ ((r0 + 32) & 7)) * 8;
  const int swz = (l31 & 7);                      // read-side row XOR key

  const int nt = bq * 2 + 2;                      // 64-kv tiles: kv < bq*128+128
  for (int t = 0; t < nt; ++t) {
    const int kv0 = t * 64;
    // ---- stage K[kv0+r][d] and V[d][kv0+s] (linear LDS, swizzled source) ----
    __builtin_amdgcn_global_load_lds(
        (const __attribute__((address_space(1))) void*)(Kbh + (size_t)(kv0 + r0) * KSTRIDE + c0),
        (__attribute__((address_space(3))) void*)(Kl + wid * 512), 16, 0, 0);
    __builtin_amdgcn_global_load_lds(
        (const __attribute__((address_space(1))) void*)(Kbh + (size_t)(kv0 + r0 + 32) * KSTRIDE + c1),
        (__attribute__((address_space(3))) void*)(Kl + 2048 + wid * 512), 16, 0, 0);
    __builtin_amdgcn_global_load_lds(
        (const __attribute__((address_space(1))) void*)(Vbh + (size_t)r0 * VSTRIDE + kv0 + c0),
        (__attribute__((address_space(3))) void*)(Vl + wid * 512), 16, 0, 0);
    __builtin_amdgcn_global_load_lds(
        (const __attribute__((address_space(1))) void*)(Vbh + (size_t)(r0 + 32) * VSTRIDE + kv0 + c1),
        (__attribute__((address_space(3))) void*)(Vl + 2048 + wid * 512), 16, 0, 0);
    __syncthreads();   // drains vmcnt -> tiles visible

#pragma unroll
    for (int ss = 0; ss < 2; ++ss) {
      const int kvs = kv0 + ss * 32;
      if (kvs <= qw) {
        // --- QK^T: A-frag from K-LDS row ss*32+l31, chunk m*2+hi (swizzled) ---
        f32x16 s;
#pragma unroll
        for (int i = 0; i < 16; ++i) s[i] = 0.f;
#pragma unroll
        for (int m = 0; m < 4; ++m) {
          const bf16x8 a = *reinterpret_cast<const bf16x8*>(
              Kl + (ss * 32 + l31) * 64 + ((m * 2 + hi) ^ swz) * 8);
          s = mfma32x32x16(a, qf[m], s);
        }

        // --- causal mask: only the diagonal tile ---
        float p[16];
        if (kvs == qw) {
#pragma unroll
          for (int r = 0; r < 16; ++r) {
            const int kvl = (r & 3) + 8 * (r >> 2) + 4 * hi;
            p[r] = (kvl <= l31) ? s[r] : -3.0e38f;
          }
        } else {
#pragma unroll
          for (int r = 0; r < 16; ++r) p[r] = s[r];
        }

        // --- row max (per q = l31) ---
        float tm = p[0];
#pragma unroll
        for (int r = 1; r < 16; ++r) tm = fmaxf(tm, p[r]);
        tm = fmaxf(tm, __shfl_xor(tm, 32));

        // --- online rescale (exact defer) ---
        if (!__all(tm <= m_st)) {
          const float m_new = fmaxf(m_st, tm);
          const float corr  = __expf(m_st - m_new);   // per-lane, q = l31
#pragma unroll
          for (int i = 0; i < 16; ++i) {
            const int qr = (i & 3) + 8 * (i >> 2) + 4 * hi;
            const float cr = __shfl(corr, qr);
            acc0[i] *= cr; acc1[i] *= cr;
          }
          l_st *= corr;
          m_st = m_new;
        }

        // --- P = exp(S - m), row sum ---
        float ls = 0.f;
#pragma unroll
        for (int r = 0; r < 16; ++r) { p[r] = __expf(p[r] - m_st); ls += p[r]; }
        ls += __shfl_xor(ls, 32);
        l_st += ls;

        // --- PV: A-frag build (verified), B-frag from V-LDS (swizzled) ---
#pragma unroll
        for (int ks = 0; ks < 2; ++ks) {
          const int bb = ks * 8;
          float u[4];
#pragma unroll
          for (int i = 0; i < 4; ++i) {
            const float tv = hi ? p[bb + i] : p[bb + 4 + i];
            u[i] = __shfl_xor(tv, 32);
          }
          bf16x8 pa;
#pragma unroll
          for (int j = 0; j < 4; ++j) {
            pa[j]     = (short)f2bf(hi ? u[j] : p[bb + j]);
            pa[4 + j] = (short)f2bf(hi ? p[bb + 4 + j] : u[j]);
          }
          const int ch = ss * 4 + ks * 2 + hi;     // s-chunk within V row
          const bf16x8 bv0 = *reinterpret_cast<const bf16x8*>(
              Vl + l31 * 64 + (ch ^ swz) * 8);
          const bf16x8 bv1 = *reinterpret_cast<const bf16x8*>(
              Vl + (32 + l31) * 64 + (ch ^ swz) * 8);
          acc0 = mfma32x32x16(pa, bv0, acc0);
          acc1 = mfma32x32x16(pa, bv1, acc1);
        }
      }
    }
    __syncthreads();   // all waves done reading before next overwrite
  }

  // --- epilogue: normalize, store O ---
  const float invl = 1.0f / l_st;
#pragma unroll
  for (int r = 0; r < 16; ++r) {
    const int qr = (r & 3) + 8 * (r >> 2) + 4 * hi;
    const float il = __shfl(invl, qr);
    unsigned short* Orow = O + baseQ + (size_t)(qw + qr) * DM;
    Orow[l31]      = f2bf(acc0[r] * il);
    Orow[32 + l31] = f2bf(acc1[r] * il);
  }
}

// ---------- launch ----------
extern "C" void kernel_launch(void* const* d_in, const int* in_sizes, int n_in,
                              void* d_out, int out_size, void* d_ws, size_t ws_size,
                              hipStream_t stream) {
  (void)in_sizes; (void)n_in; (void)out_size; (void)ws_size;
  constexpr int Bx = 4, S = 2048, DM = 1024;
  constexpr int M = Bx * S;          // 8192
  constexpr size_t XEL = (size_t)M * DM;       // 8388608
  constexpr size_t WEL = (size_t)DM * DM;      // 1048576

  const float* Wq = (const float*)d_in[1];
  const float* Wk = (const float*)d_in[2];
  const float* Wv = (const float*)d_in[3];
  const float* Wo = (const float*)d_in[4];
  const float* Xf = (const float*)d_in[5];
  float* out = (float*)d_out;

  char* ws = (char*)d_ws;
  unsigned short* Xbf = (unsigned short*)(ws + 0);           // 16 MB (reused as attn-out)
  unsigned short* Qb  = (unsigned short*)(ws + 16777216);    // [8192][1024]
  unsigned short* Kb  = (unsigned short*)(ws + 33554432);    // [8192][1056] padded
  unsigned short* Vtb = (unsigned short*)(ws + 50855936);    // [4096][2080] padded V^T
  unsigned short* Wqb = (unsigned short*)(ws + 67895296);
  unsigned short* Wkb = (unsigned short*)(ws + 69992448);
  unsigned short* Wvb = (unsigned short*)(ws + 72089600);
  unsigned short* Wob = (unsigned short*)(ws + 74186752);
  unsigned short* Ob  = Xbf;   // alias: X dead after V projection

  // 1) convert inputs to bf16
  cvt_f32_bf16<<<(int)(XEL / 1024), 256, 0, stream>>>(Xf, Xbf, (int)XEL);
  cvt_f32_bf16<<<(int)(WEL / 1024), 256, 0, stream>>>(Wq, Wqb, (int)WEL);
  cvt_f32_bf16<<<(int)(WEL / 1024), 256, 0, stream>>>(Wk, Wkb, (int)WEL);
  cvt_f32_bf16<<<(int)(WEL / 1024), 256, 0, stream>>>(Wv, Wvb, (int)WEL);
  cvt_f32_bf16<<<(int)(WEL / 1024), 256, 0, stream>>>(Wo, Wob, (int)WEL);

  // 2) projections: Q (scaled 1/8), K (padded rows), V (transposed+padded)
  dim3 gg(DM / 128, M / 128);   // (8, 64)
  gemm_bt<3><<<gg, 256, 0, stream>>>(Xbf, Wqb, Qb, M, DM, DM);
  gemm_bt<4><<<gg, 256, 0, stream>>>(Xbf, Wkb, Kb, M, DM, DM);
  gemm_bt<2><<<gg, 256, 0, stream>>>(Xbf, Wvb, Vtb, M, DM, DM);

  // 3) causal flash attention (writes Ob, aliasing Xbf)
  attn_fwd<<<Bx * 16 * (S / 128), 256, 0, stream>>>(Qb, Kb, Vtb, Ob);

  // 4) output projection (f32 out)
  gemm_bt<1><<<gg, 256, 0, stream>>>(Ob, Wob, out, M, DM, DM);
}

// Round 8
// 339.136 us; speedup vs baseline: 2.3691x; 1.2258x over previous
//
#include <hip/hip_runtime.h>
#include <hip/hip_bf16.h>
#include <cstdint>
#include <cstddef>

// ---------- types ----------
typedef short bf16x8 __attribute__((ext_vector_type(8)));     // 8 bf16 in 4 VGPRs
typedef float f32x4 __attribute__((ext_vector_type(4)));
typedef float f32x16 __attribute__((ext_vector_type(16)));
typedef unsigned short u16x4 __attribute__((ext_vector_type(4)));

__device__ __forceinline__ unsigned short f2bf(float f) {
  unsigned int u = __builtin_bit_cast(unsigned int, f);
  u = (u + 0x7FFFu + ((u >> 16) & 1u)) >> 16;   // RNE
  return (unsigned short)u;
}

__device__ __forceinline__ f32x4 mfma16x16x32(bf16x8 a, bf16x8 b, f32x4 c) {
  return __builtin_amdgcn_mfma_f32_16x16x32_bf16(a, b, c, 0, 0, 0);
}
__device__ __forceinline__ f32x16 mfma32x32x16(bf16x8 a, bf16x8 b, f32x16 c) {
  return __builtin_amdgcn_mfma_f32_32x32x16_bf16(a, b, c, 0, 0, 0);
}

// padded strides (elements); 16B-aligned
constexpr int KSTRIDE = 1056;   // K rows: 2112 B
constexpr int VSTRIDE = 2080;   // V^T rows: 4160 B

// ---------- f32 -> bf16 conversion ----------
__global__ __launch_bounds__(256) void cvt_f32_bf16(const float* __restrict__ src,
                                                    unsigned short* __restrict__ dst, int n) {
  int i = (blockIdx.x * 256 + threadIdx.x) * 4;
  if (i + 3 < n) {
    float4 v = *reinterpret_cast<const float4*>(src + i);
    u16x4 o;
    o[0] = f2bf(v.x); o[1] = f2bf(v.y); o[2] = f2bf(v.z); o[3] = f2bf(v.w);
    *reinterpret_cast<u16x4*>(dst + i) = o;
  }
}

// ---------- GEMM: C[M,N] = A[M,K] * Bw[N,K]^T  (bf16 in, f32 accum) ----------
// OUTMODE: 0 = bf16 row-major stride N
//          1 = f32 row-major stride N
//          2 = bf16 V-transposed PADDED: out[((row>>11)*1024 + col)*VSTRIDE + (row&2047)]
//          3 = bf16 row-major, values * 0.125 (Q projection, folds attn scale)
//          4 = bf16 row-major PADDED stride KSTRIDE (K projection)
template <int OUTMODE>
__global__ __launch_bounds__(256) void gemm_bt(const unsigned short* __restrict__ A,
                                               const unsigned short* __restrict__ Bw,
                                               void* __restrict__ Cp,
                                               int M, int N, int K) {
  __shared__ unsigned short As[128 * 32];
  __shared__ unsigned short Bs[128 * 32];
  const int tid  = threadIdx.x;
  const int lane = tid & 63, wid = tid >> 6;
  const int g = lane >> 4, cc = lane & 15;
  const int wr = wid >> 1, wc = wid & 1;
  const int m0 = blockIdx.y * 128, n0 = blockIdx.x * 128;
  const int arow = tid >> 2;          // 0..63
  const int acol = (tid & 3) * 8;     // 0,8,16,24

  const unsigned short* gA = A  + (size_t)(m0 + arow) * K + acol;
  const unsigned short* gB = Bw + (size_t)(n0 + arow) * K + acol;

  f32x4 acc[4][4];
#pragma unroll
  for (int i = 0; i < 4; ++i)
#pragma unroll
    for (int j = 0; j < 4; ++j) acc[i][j] = f32x4{0.f, 0.f, 0.f, 0.f};

  for (int k0 = 0; k0 < K; k0 += 32) {
    __builtin_amdgcn_global_load_lds(
        (const __attribute__((address_space(1))) void*)(gA + k0),
        (__attribute__((address_space(3))) void*)(As + wid * 512), 16, 0, 0);
    __builtin_amdgcn_global_load_lds(
        (const __attribute__((address_space(1))) void*)(gA + (size_t)64 * K + k0),
        (__attribute__((address_space(3))) void*)(As + 2048 + wid * 512), 16, 0, 0);
    __builtin_amdgcn_global_load_lds(
        (const __attribute__((address_space(1))) void*)(gB + k0),
        (__attribute__((address_space(3))) void*)(Bs + wid * 512), 16, 0, 0);
    __builtin_amdgcn_global_load_lds(
        (const __attribute__((address_space(1))) void*)(gB + (size_t)64 * K + k0),
        (__attribute__((address_space(3))) void*)(Bs + 2048 + wid * 512), 16, 0, 0);
    __syncthreads();

    bf16x8 af[4], bfv[4];
#pragma unroll
    for (int mi = 0; mi < 4; ++mi)
      af[mi] = *reinterpret_cast<const bf16x8*>(As + (wr * 64 + mi * 16 + cc) * 32 + g * 8);
#pragma unroll
    for (int ni = 0; ni < 4; ++ni)
      bfv[ni] = *reinterpret_cast<const bf16x8*>(Bs + (wc * 64 + ni * 16 + cc) * 32 + g * 8);
#pragma unroll
    for (int mi = 0; mi < 4; ++mi)
#pragma unroll
      for (int ni = 0; ni < 4; ++ni)
        acc[mi][ni] = mfma16x16x32(af[mi], bfv[ni], acc[mi][ni]);
    __syncthreads();
  }

  // epilogue: D row = (lane>>4)*4 + r, col = lane&15  (verified mapping)
#pragma unroll
  for (int mi = 0; mi < 4; ++mi) {
#pragma unroll
    for (int ni = 0; ni < 4; ++ni) {
      const int row0 = m0 + wr * 64 + mi * 16 + g * 4;
      const int col  = n0 + wc * 64 + ni * 16 + cc;
      if (OUTMODE == 2) {
        u16x4 o;
#pragma unroll
        for (int r = 0; r < 4; ++r) o[r] = f2bf(acc[mi][ni][r]);
        const size_t idx = ((size_t)(row0 >> 11) * 1024 + col) * VSTRIDE + (row0 & 2047);
        *reinterpret_cast<u16x4*>(reinterpret_cast<unsigned short*>(Cp) + idx) = o;
      } else {
#pragma unroll
        for (int r = 0; r < 4; ++r) {
          const int row = row0 + r;
          if (OUTMODE == 1)
            reinterpret_cast<float*>(Cp)[(size_t)row * N + col] = acc[mi][ni][r];
          else if (OUTMODE == 3)
            reinterpret_cast<unsigned short*>(Cp)[(size_t)row * N + col] = f2bf(acc[mi][ni][r] * 0.125f);
          else if (OUTMODE == 4)
            reinterpret_cast<unsigned short*>(Cp)[(size_t)row * KSTRIDE + col] = f2bf(acc[mi][ni][r]);
          else
            reinterpret_cast<unsigned short*>(Cp)[(size_t)row * N + col] = f2bf(acc[mi][ni][r]);
        }
      }
    }
  }
}

// ---------- causal flash attention, 32x32 MFMA, 2-phase double-buffered LDS ----------
// Q: [B*S][1024] bf16, pre-scaled 0.125; K: [B*S][KSTRIDE] padded; Vt: per (b,h)
// [64][VSTRIDE]; O: [B*S][1024].
//
// Block = 4 waves, one (b,h). Causal pairing: block processes q-tiles {pr, 15-pr}
// sequentially -> uniform 34 tile-units of work per block (fixes dispatch tail).
// Per 64-kv tile: 2-phase pipeline (T3 minimum): issue next-tile global_load_lds
// into buf^1 BEFORE computing buf -> HBM latency hides under compute; ONE barrier
// per tile. LDS chunk-swizzle: linear dest, source chunk ^= row&7, reads ^ swz
// (rule #21 both-sides).
//
// Math (verified r6/r7): D[kv][q] = mfma(K,Q); lane softmax state is column q=lane&31;
// acc rows are q_row=(i&3)+8*(i>>2)+4*hi -> per-q corrections shuffled from lane q_row.
__global__ __launch_bounds__(256) void attn_fwd(const unsigned short* __restrict__ Q,
                                                const unsigned short* __restrict__ Kp,
                                                const unsigned short* __restrict__ Vt,
                                                unsigned short* __restrict__ O) {
  constexpr int S = 2048, DM = 1024;
  __shared__ unsigned short Kl[2][64 * 64];   // 2 x 8KB
  __shared__ unsigned short Vl[2][64 * 64];   // 2 x 8KB
  const int tid  = threadIdx.x;
  const int lane = tid & 63, wid = tid >> 6;
  const int l31 = lane & 31, hi = lane >> 5;
  const int pr = blockIdx.x & 7;            // pair index
  const int h  = (blockIdx.x >> 3) & 15;
  const int b  = blockIdx.x >> 7;

  const size_t baseQ = (size_t)b * S * DM + (size_t)h * 64;
  const unsigned short* Kbh = Kp + (size_t)b * S * KSTRIDE + (size_t)h * 64;
  const unsigned short* Vbh = Vt + (size_t)((b * 16 + h) * 64) * VSTRIDE;

  // staging coords: thread covers row r0 / r0+32, chunk sc (16B)
  const int r0 = wid * 8 + (lane >> 3);
  const int sc = lane & 7;
  const int c0 = (sc ^ (r0 & 7)) * 8;            // pre-swizzled source chunk (elems)
  const int c1 = (sc ^ ((r0 + 32) & 7)) * 8;
  const int swz = (l31 & 7);                      // read-side row XOR key

  auto STAGE = [&](int bf, int t) {
    const int kv0 = t * 64;
    __builtin_amdgcn_global_load_lds(
        (const __attribute__((address_space(1))) void*)(Kbh + (size_t)(kv0 + r0) * KSTRIDE + c0),
        (__attribute__((address_space(3))) void*)(&Kl[bf][wid * 512]), 16, 0, 0);
    __builtin_amdgcn_global_load_lds(
        (const __attribute__((address_space(1))) void*)(Kbh + (size_t)(kv0 + r0 + 32) * KSTRIDE + c1),
        (__attribute__((address_space(3))) void*)(&Kl[bf][2048 + wid * 512]), 16, 0, 0);
    __builtin_amdgcn_global_load_lds(
        (const __attribute__((address_space(1))) void*)(Vbh + (size_t)r0 * VSTRIDE + kv0 + c0),
        (__attribute__((address_space(3))) void*)(&Vl[bf][wid * 512]), 16, 0, 0);
    __builtin_amdgcn_global_load_lds(
        (const __attribute__((address_space(1))) void*)(Vbh + (size_t)(r0 + 32) * VSTRIDE + kv0 + c1),
        (__attribute__((address_space(3))) void*)(&Vl[bf][2048 + wid * 512]), 16, 0, 0);
  };

  int cur = 0;
  for (int half = 0; half < 2; ++half) {
    const int bqt = half ? (15 - pr) : pr;
    const int qw  = bqt * 128 + wid * 32;     // this wave's q-base

    // hoist Q fragments (B-operand: lane holds Q[qw+l31][m*16 + hi*8 + j])
    const unsigned short* Qrow = Q + baseQ + (size_t)(qw + l31) * DM + hi * 8;
    bf16x8 qf[4];
#pragma unroll
    for (int m = 0; m < 4; ++m) qf[m] = *reinterpret_cast<const bf16x8*>(Qrow + m * 16);

    f32x16 acc0, acc1;
#pragma unroll
    for (int i = 0; i < 16; ++i) { acc0[i] = 0.f; acc1[i] = 0.f; }
    float m_st = -3.0e38f, l_st = 0.f;

    const int nt = bqt * 2 + 2;               // 64-kv tiles
    STAGE(cur, 0);
    __syncthreads();                          // tile 0 visible

    for (int t = 0; t < nt; ++t) {
      if (t + 1 < nt) STAGE(cur ^ 1, t + 1);  // issue next tile BEFORE compute
      const int kv0 = t * 64;

#pragma unroll
      for (int ss = 0; ss < 2; ++ss) {
        const int kvs = kv0 + ss * 32;
        if (kvs <= qw) {
          // --- QK^T: A-frag from K-LDS row ss*32+l31, chunk (m*2+hi)^swz ---
          f32x16 s;
#pragma unroll
          for (int i = 0; i < 16; ++i) s[i] = 0.f;
#pragma unroll
          for (int m = 0; m < 4; ++m) {
            const bf16x8 a = *reinterpret_cast<const bf16x8*>(
                &Kl[cur][(ss * 32 + l31) * 64 + ((m * 2 + hi) ^ swz) * 8]);
            s = mfma32x32x16(a, qf[m], s);
          }

          // --- causal mask: only the diagonal tile ---
          float p[16];
          if (kvs == qw) {
#pragma unroll
            for (int r = 0; r < 16; ++r) {
              const int kvl = (r & 3) + 8 * (r >> 2) + 4 * hi;
              p[r] = (kvl <= l31) ? s[r] : -3.0e38f;
            }
          } else {
#pragma unroll
            for (int r = 0; r < 16; ++r) p[r] = s[r];
          }

          // --- row max (per q = l31) ---
          float tm = p[0];
#pragma unroll
          for (int r = 1; r < 16; ++r) tm = fmaxf(tm, p[r]);
          tm = fmaxf(tm, __shfl_xor(tm, 32));

          // --- online rescale (exact defer) ---
          if (!__all(tm <= m_st)) {
            const float m_new = fmaxf(m_st, tm);
            const float corr  = __expf(m_st - m_new);   // per-lane, q = l31
#pragma unroll
            for (int i = 0; i < 16; ++i) {
              const int qr = (i & 3) + 8 * (i >> 2) + 4 * hi;
              const float cr = __shfl(corr, qr);
              acc0[i] *= cr; acc1[i] *= cr;
            }
            l_st *= corr;
            m_st = m_new;
          }

          // --- P = exp(S - m), row sum ---
          float ls = 0.f;
#pragma unroll
          for (int r = 0; r < 16; ++r) { p[r] = __expf(p[r] - m_st); ls += p[r]; }
          ls += __shfl_xor(ls, 32);
          l_st += ls;

          // --- PV: A-frag build (verified), B-frag from V-LDS (swizzled) ---
#pragma unroll
          for (int ks = 0; ks < 2; ++ks) {
            const int bb = ks * 8;
            float u[4];
#pragma unroll
            for (int i = 0; i < 4; ++i) {
              const float tv = hi ? p[bb + i] : p[bb + 4 + i];
              u[i] = __shfl_xor(tv, 32);
            }
            bf16x8 pa;
#pragma unroll
            for (int j = 0; j < 4; ++j) {
              pa[j]     = (short)f2bf(hi ? u[j] : p[bb + j]);
              pa[4 + j] = (short)f2bf(hi ? p[bb + 4 + j] : u[j]);
            }
            const int ch = ss * 4 + ks * 2 + hi;     // s-chunk within V row
            const bf16x8 bv0 = *reinterpret_cast<const bf16x8*>(
                &Vl[cur][l31 * 64 + (ch ^ swz) * 8]);
            const bf16x8 bv1 = *reinterpret_cast<const bf16x8*>(
                &Vl[cur][(32 + l31) * 64 + (ch ^ swz) * 8]);
            acc0 = mfma32x32x16(pa, bv0, acc0);
            acc1 = mfma32x32x16(pa, bv1, acc1);
          }
        }
      }
      __syncthreads();   // drains vmcnt (t+1 staged) + all reads of buf[cur] done
      cur ^= 1;
    }

    // --- epilogue: normalize, store O for this q-tile ---
    const float invl = 1.0f / l_st;
#pragma unroll
    for (int r = 0; r < 16; ++r) {
      const int qr = (r & 3) + 8 * (r >> 2) + 4 * hi;
      const float il = __shfl(invl, qr);
      unsigned short* Orow = O + baseQ + (size_t)(qw + qr) * DM;
      Orow[l31]      = f2bf(acc0[r] * il);
      Orow[32 + l31] = f2bf(acc1[r] * il);
    }
  }
}

// ---------- launch ----------
extern "C" void kernel_launch(void* const* d_in, const int* in_sizes, int n_in,
                              void* d_out, int out_size, void* d_ws, size_t ws_size,
                              hipStream_t stream) {
  (void)in_sizes; (void)n_in; (void)out_size; (void)ws_size;
  constexpr int Bx = 4, S = 2048, DM = 1024;
  constexpr int M = Bx * S;          // 8192
  constexpr size_t XEL = (size_t)M * DM;       // 8388608
  constexpr size_t WEL = (size_t)DM * DM;      // 1048576

  const float* Wq = (const float*)d_in[1];
  const float* Wk = (const float*)d_in[2];
  const float* Wv = (const float*)d_in[3];
  const float* Wo = (const float*)d_in[4];
  const float* Xf = (const float*)d_in[5];
  float* out = (float*)d_out;

  char* ws = (char*)d_ws;
  unsigned short* Xbf = (unsigned short*)(ws + 0);           // 16 MB (reused as attn-out)
  unsigned short* Qb  = (unsigned short*)(ws + 16777216);    // [8192][1024]
  unsigned short* Kb  = (unsigned short*)(ws + 33554432);    // [8192][1056] padded
  unsigned short* Vtb = (unsigned short*)(ws + 50855936);    // [4096][2080] padded V^T
  unsigned short* Wqb = (unsigned short*)(ws + 67895296);
  unsigned short* Wkb = (unsigned short*)(ws + 69992448);
  unsigned short* Wvb = (unsigned short*)(ws + 72089600);
  unsigned short* Wob = (unsigned short*)(ws + 74186752);
  unsigned short* Ob  = Xbf;   // alias: X dead after V projection

  // 1) convert inputs to bf16
  cvt_f32_bf16<<<(int)(XEL / 1024), 256, 0, stream>>>(Xf, Xbf, (int)XEL);
  cvt_f32_bf16<<<(int)(WEL / 1024), 256, 0, stream>>>(Wq, Wqb, (int)WEL);
  cvt_f32_bf16<<<(int)(WEL / 1024), 256, 0, stream>>>(Wk, Wkb, (int)WEL);
  cvt_f32_bf16<<<(int)(WEL / 1024), 256, 0, stream>>>(Wv, Wvb, (int)WEL);
  cvt_f32_bf16<<<(int)(WEL / 1024), 256, 0, stream>>>(Wo, Wob, (int)WEL);

  // 2) projections: Q (scaled 1/8), K (padded rows), V (transposed+padded)
  dim3 gg(DM / 128, M / 128);   // (8, 64)
  gemm_bt<3><<<gg, 256, 0, stream>>>(Xbf, Wqb, Qb, M, DM, DM);
  gemm_bt<4><<<gg, 256, 0, stream>>>(Xbf, Wkb, Kb, M, DM, DM);
  gemm_bt<2><<<gg, 256, 0, stream>>>(Xbf, Wvb, Vtb, M, DM, DM);

  // 3) causal flash attention: 512 blocks, uniform work via {pr, 15-pr} pairing
  attn_fwd<<<Bx * 16 * 8, 256, 0, stream>>>(Qb, Kb, Vtb, Ob);

  // 4) output projection (f32 out)
  gemm_bt<1><<<gg, 256, 0, stream>>>(Ob, Wob, out, M, DM, DM);
}

// Round 9
// 312.517 us; speedup vs baseline: 2.5709x; 1.0852x over previous
//
#include <hip/hip_runtime.h>
#include <hip/hip_bf16.h>
#include <cstdint>
#include <cstddef>

// ---------- types ----------
typedef short bf16x8 __attribute__((ext_vector_type(8)));     // 8 bf16 in 4 VGPRs
typedef float f32x4 __attribute__((ext_vector_type(4)));
typedef float f32x16 __attribute__((ext_vector_type(16)));
typedef unsigned short u16x4 __attribute__((ext_vector_type(4)));

__device__ __forceinline__ unsigned short f2bf(float f) {
  unsigned int u = __builtin_bit_cast(unsigned int, f);
  u = (u + 0x7FFFu + ((u >> 16) & 1u)) >> 16;   // RNE
  return (unsigned short)u;
}

__device__ __forceinline__ f32x4 mfma16x16x32(bf16x8 a, bf16x8 b, f32x4 c) {
  return __builtin_amdgcn_mfma_f32_16x16x32_bf16(a, b, c, 0, 0, 0);
}
__device__ __forceinline__ f32x16 mfma32x32x16(bf16x8 a, bf16x8 b, f32x16 c) {
  return __builtin_amdgcn_mfma_f32_32x32x16_bf16(a, b, c, 0, 0, 0);
}

// padded strides (elements); 16B-aligned
constexpr int KSTRIDE = 1056;   // K rows: 2112 B
constexpr int VSTRIDE = 2080;   // V^T rows: 4160 B

// ---------- f32 -> bf16 conversion ----------
__global__ __launch_bounds__(256) void cvt_f32_bf16(const float* __restrict__ src,
                                                    unsigned short* __restrict__ dst, int n) {
  int i = (blockIdx.x * 256 + threadIdx.x) * 4;
  if (i + 3 < n) {
    float4 v = *reinterpret_cast<const float4*>(src + i);
    u16x4 o;
    o[0] = f2bf(v.x); o[1] = f2bf(v.y); o[2] = f2bf(v.z); o[3] = f2bf(v.w);
    *reinterpret_cast<u16x4*>(dst + i) = o;
  }
}

// convert 4 weight matrices (1M elems each) in one launch; dst contiguous
__global__ __launch_bounds__(256) void cvt_w4(const float* __restrict__ w0,
                                              const float* __restrict__ w1,
                                              const float* __restrict__ w2,
                                              const float* __restrict__ w3,
                                              unsigned short* __restrict__ dst) {
  constexpr int WEL = 1024 * 1024;
  int i = (blockIdx.x * 256 + threadIdx.x) * 4;       // 0 .. 4*WEL
  const int sel = i >> 20;                             // which weight
  const float* src = sel == 0 ? w0 : sel == 1 ? w1 : sel == 2 ? w2 : w3;
  float4 v = *reinterpret_cast<const float4*>(src + (i & (WEL - 1)));
  u16x4 o;
  o[0] = f2bf(v.x); o[1] = f2bf(v.y); o[2] = f2bf(v.z); o[3] = f2bf(v.w);
  *reinterpret_cast<u16x4*>(dst + i) = o;
}

// ---------- fused QKV GEMM: C = X[8192,1024] @ Wqkv[3072,1024]^T ----------
// 2-phase double-buffered staging (T3 minimum). Per-block epilogue mode by n0>>10:
//   0: Q -> Qb row-major stride 1024, *0.125 (folds attn scale)
//   1: K -> Kb row-major padded stride KSTRIDE
//   2: V -> Vtb transposed per (b,h): idx = ((row>>11)*1024 + colh)*VSTRIDE + (row&2047)
__global__ __launch_bounds__(256) void gemm_qkv(const unsigned short* __restrict__ A,
                                                const unsigned short* __restrict__ Wf,
                                                unsigned short* __restrict__ Qb,
                                                unsigned short* __restrict__ Kb,
                                                unsigned short* __restrict__ Vtb) {
  constexpr int K = 1024;
  __shared__ unsigned short As[2][128 * 32];
  __shared__ unsigned short Bs[2][128 * 32];
  const int tid  = threadIdx.x;
  const int lane = tid & 63, wid = tid >> 6;
  const int g = lane >> 4, cc = lane & 15;
  const int wr = wid >> 1, wc = wid & 1;
  const int m0 = blockIdx.y * 128, n0 = blockIdx.x * 128;
  const int arow = tid >> 2;
  const int acol = (tid & 3) * 8;

  const unsigned short* gA = A  + (size_t)(m0 + arow) * K + acol;
  const unsigned short* gB = Wf + (size_t)(n0 + arow) * K + acol;

  f32x4 acc[4][4];
#pragma unroll
  for (int i = 0; i < 4; ++i)
#pragma unroll
    for (int j = 0; j < 4; ++j) acc[i][j] = f32x4{0.f, 0.f, 0.f, 0.f};

  auto STAGE = [&](int bf, int k0) {
    __builtin_amdgcn_global_load_lds(
        (const __attribute__((address_space(1))) void*)(gA + k0),
        (__attribute__((address_space(3))) void*)(&As[bf][wid * 512]), 16, 0, 0);
    __builtin_amdgcn_global_load_lds(
        (const __attribute__((address_space(1))) void*)(gA + (size_t)64 * K + k0),
        (__attribute__((address_space(3))) void*)(&As[bf][2048 + wid * 512]), 16, 0, 0);
    __builtin_amdgcn_global_load_lds(
        (const __attribute__((address_space(1))) void*)(gB + k0),
        (__attribute__((address_space(3))) void*)(&Bs[bf][wid * 512]), 16, 0, 0);
    __builtin_amdgcn_global_load_lds(
        (const __attribute__((address_space(1))) void*)(gB + (size_t)64 * K + k0),
        (__attribute__((address_space(3))) void*)(&Bs[bf][2048 + wid * 512]), 16, 0, 0);
  };

  int cur = 0;
  STAGE(0, 0);
  __syncthreads();
  for (int t = 0; t < K / 32; ++t) {
    if (t + 1 < K / 32) STAGE(cur ^ 1, (t + 1) * 32);
    bf16x8 af[4], bfv[4];
#pragma unroll
    for (int mi = 0; mi < 4; ++mi)
      af[mi] = *reinterpret_cast<const bf16x8*>(&As[cur][(wr * 64 + mi * 16 + cc) * 32 + g * 8]);
#pragma unroll
    for (int ni = 0; ni < 4; ++ni)
      bfv[ni] = *reinterpret_cast<const bf16x8*>(&Bs[cur][(wc * 64 + ni * 16 + cc) * 32 + g * 8]);
#pragma unroll
    for (int mi = 0; mi < 4; ++mi)
#pragma unroll
      for (int ni = 0; ni < 4; ++ni)
        acc[mi][ni] = mfma16x16x32(af[mi], bfv[ni], acc[mi][ni]);
    __syncthreads();   // drains vmcnt (t+1 staged) + reads of buf[cur] done
    cur ^= 1;
  }

  const int mode = n0 >> 10;       // 0=Q, 1=K, 2=V (wave-uniform)
  const int nh   = n0 & 1023;      // column base within the 1024-wide output
#pragma unroll
  for (int mi = 0; mi < 4; ++mi) {
#pragma unroll
    for (int ni = 0; ni < 4; ++ni) {
      const int row0 = m0 + wr * 64 + mi * 16 + g * 4;
      const int col  = nh + wc * 64 + ni * 16 + cc;
      if (mode == 2) {
        u16x4 o;
#pragma unroll
        for (int r = 0; r < 4; ++r) o[r] = f2bf(acc[mi][ni][r]);
        const size_t idx = ((size_t)(row0 >> 11) * 1024 + col) * VSTRIDE + (row0 & 2047);
        *reinterpret_cast<u16x4*>(Vtb + idx) = o;
      } else if (mode == 1) {
#pragma unroll
        for (int r = 0; r < 4; ++r)
          Kb[(size_t)(row0 + r) * KSTRIDE + col] = f2bf(acc[mi][ni][r]);
      } else {
#pragma unroll
        for (int r = 0; r < 4; ++r)
          Qb[(size_t)(row0 + r) * 1024 + col] = f2bf(acc[mi][ni][r] * 0.125f);
      }
    }
  }
}

// ---------- O-projection GEMM: out_f32 = Ob[8192,1024] @ Wo[1024,1024]^T ----------
__global__ __launch_bounds__(256) void gemm_op(const unsigned short* __restrict__ A,
                                               const unsigned short* __restrict__ Bw,
                                               float* __restrict__ Cp) {
  constexpr int K = 1024, N = 1024;
  __shared__ unsigned short As[2][128 * 32];
  __shared__ unsigned short Bs[2][128 * 32];
  const int tid  = threadIdx.x;
  const int lane = tid & 63, wid = tid >> 6;
  const int g = lane >> 4, cc = lane & 15;
  const int wr = wid >> 1, wc = wid & 1;
  const int m0 = blockIdx.y * 128, n0 = blockIdx.x * 128;
  const int arow = tid >> 2;
  const int acol = (tid & 3) * 8;

  const unsigned short* gA = A  + (size_t)(m0 + arow) * K + acol;
  const unsigned short* gB = Bw + (size_t)(n0 + arow) * K + acol;

  f32x4 acc[4][4];
#pragma unroll
  for (int i = 0; i < 4; ++i)
#pragma unroll
    for (int j = 0; j < 4; ++j) acc[i][j] = f32x4{0.f, 0.f, 0.f, 0.f};

  auto STAGE = [&](int bf, int k0) {
    __builtin_amdgcn_global_load_lds(
        (const __attribute__((address_space(1))) void*)(gA + k0),
        (__attribute__((address_space(3))) void*)(&As[bf][wid * 512]), 16, 0, 0);
    __builtin_amdgcn_global_load_lds(
        (const __attribute__((address_space(1))) void*)(gA + (size_t)64 * K + k0),
        (__attribute__((address_space(3))) void*)(&As[bf][2048 + wid * 512]), 16, 0, 0);
    __builtin_amdgcn_global_load_lds(
        (const __attribute__((address_space(1))) void*)(gB + k0),
        (__attribute__((address_space(3))) void*)(&Bs[bf][wid * 512]), 16, 0, 0);
    __builtin_amdgcn_global_load_lds(
        (const __attribute__((address_space(1))) void*)(gB + (size_t)64 * K + k0),
        (__attribute__((address_space(3))) void*)(&Bs[bf][2048 + wid * 512]), 16, 0, 0);
  };

  int cur = 0;
  STAGE(0, 0);
  __syncthreads();
  for (int t = 0; t < K / 32; ++t) {
    if (t + 1 < K / 32) STAGE(cur ^ 1, (t + 1) * 32);
    bf16x8 af[4], bfv[4];
#pragma unroll
    for (int mi = 0; mi < 4; ++mi)
      af[mi] = *reinterpret_cast<const bf16x8*>(&As[cur][(wr * 64 + mi * 16 + cc) * 32 + g * 8]);
#pragma unroll
    for (int ni = 0; ni < 4; ++ni)
      bfv[ni] = *reinterpret_cast<const bf16x8*>(&Bs[cur][(wc * 64 + ni * 16 + cc) * 32 + g * 8]);
#pragma unroll
    for (int mi = 0; mi < 4; ++mi)
#pragma unroll
      for (int ni = 0; ni < 4; ++ni)
        acc[mi][ni] = mfma16x16x32(af[mi], bfv[ni], acc[mi][ni]);
    __syncthreads();
    cur ^= 1;
  }

#pragma unroll
  for (int mi = 0; mi < 4; ++mi) {
#pragma unroll
    for (int ni = 0; ni < 4; ++ni) {
      const int row0 = m0 + wr * 64 + mi * 16 + g * 4;
      const int col  = n0 + wc * 64 + ni * 16 + cc;
#pragma unroll
      for (int r = 0; r < 4; ++r)
        Cp[(size_t)(row0 + r) * N + col] = acc[mi][ni][r];
    }
  }
}

// ---------- causal flash attention, 32x32 MFMA, 2-phase double-buffered LDS ----------
// (verified r8: math/layouts unchanged)
__global__ __launch_bounds__(256) void attn_fwd(const unsigned short* __restrict__ Q,
                                                const unsigned short* __restrict__ Kp,
                                                const unsigned short* __restrict__ Vt,
                                                unsigned short* __restrict__ O) {
  constexpr int S = 2048, DM = 1024;
  __shared__ unsigned short Kl[2][64 * 64];   // 2 x 8KB
  __shared__ unsigned short Vl[2][64 * 64];   // 2 x 8KB
  const int tid  = threadIdx.x;
  const int lane = tid & 63, wid = tid >> 6;
  const int l31 = lane & 31, hi = lane >> 5;
  const int pr = blockIdx.x & 7;            // pair index
  const int h  = (blockIdx.x >> 3) & 15;
  const int b  = blockIdx.x >> 7;

  const size_t baseQ = (size_t)b * S * DM + (size_t)h * 64;
  const unsigned short* Kbh = Kp + (size_t)b * S * KSTRIDE + (size_t)h * 64;
  const unsigned short* Vbh = Vt + (size_t)((b * 16 + h) * 64) * VSTRIDE;

  const int r0 = wid * 8 + (lane >> 3);
  const int sc = lane & 7;
  const int c0 = (sc ^ (r0 & 7)) * 8;
  const int c1 = (sc ^ ((r0 + 32) & 7)) * 8;
  const int swz = (l31 & 7);

  auto STAGE = [&](int bf, int t) {
    const int kv0 = t * 64;
    __builtin_amdgcn_global_load_lds(
        (const __attribute__((address_space(1))) void*)(Kbh + (size_t)(kv0 + r0) * KSTRIDE + c0),
        (__attribute__((address_space(3))) void*)(&Kl[bf][wid * 512]), 16, 0, 0);
    __builtin_amdgcn_global_load_lds(
        (const __attribute__((address_space(1))) void*)(Kbh + (size_t)(kv0 + r0 + 32) * KSTRIDE + c1),
        (__attribute__((address_space(3))) void*)(&Kl[bf][2048 + wid * 512]), 16, 0, 0);
    __builtin_amdgcn_global_load_lds(
        (const __attribute__((address_space(1))) void*)(Vbh + (size_t)r0 * VSTRIDE + kv0 + c0),
        (__attribute__((address_space(3))) void*)(&Vl[bf][wid * 512]), 16, 0, 0);
    __builtin_amdgcn_global_load_lds(
        (const __attribute__((address_space(1))) void*)(Vbh + (size_t)(r0 + 32) * VSTRIDE + kv0 + c1),
        (__attribute__((address_space(3))) void*)(&Vl[bf][2048 + wid * 512]), 16, 0, 0);
  };

  int cur = 0;
  for (int half = 0; half < 2; ++half) {
    const int bqt = half ? (15 - pr) : pr;
    const int qw  = bqt * 128 + wid * 32;

    const unsigned short* Qrow = Q + baseQ + (size_t)(qw + l31) * DM + hi * 8;
    bf16x8 qf[4];
#pragma unroll
    for (int m = 0; m < 4; ++m) qf[m] = *reinterpret_cast<const bf16x8*>(Qrow + m * 16);

    f32x16 acc0, acc1;
#pragma unroll
    for (int i = 0; i < 16; ++i) { acc0[i] = 0.f; acc1[i] = 0.f; }
    float m_st = -3.0e38f, l_st = 0.f;

    const int nt = bqt * 2 + 2;
    STAGE(cur, 0);
    __syncthreads();

    for (int t = 0; t < nt; ++t) {
      if (t + 1 < nt) STAGE(cur ^ 1, t + 1);
      const int kv0 = t * 64;

#pragma unroll
      for (int ss = 0; ss < 2; ++ss) {
        const int kvs = kv0 + ss * 32;
        if (kvs <= qw) {
          f32x16 s;
#pragma unroll
          for (int i = 0; i < 16; ++i) s[i] = 0.f;
#pragma unroll
          for (int m = 0; m < 4; ++m) {
            const bf16x8 a = *reinterpret_cast<const bf16x8*>(
                &Kl[cur][(ss * 32 + l31) * 64 + ((m * 2 + hi) ^ swz) * 8]);
            s = mfma32x32x16(a, qf[m], s);
          }

          float p[16];
          if (kvs == qw) {
#pragma unroll
            for (int r = 0; r < 16; ++r) {
              const int kvl = (r & 3) + 8 * (r >> 2) + 4 * hi;
              p[r] = (kvl <= l31) ? s[r] : -3.0e38f;
            }
          } else {
#pragma unroll
            for (int r = 0; r < 16; ++r) p[r] = s[r];
          }

          float tm = p[0];
#pragma unroll
          for (int r = 1; r < 16; ++r) tm = fmaxf(tm, p[r]);
          tm = fmaxf(tm, __shfl_xor(tm, 32));

          if (!__all(tm <= m_st)) {
            const float m_new = fmaxf(m_st, tm);
            const float corr  = __expf(m_st - m_new);
#pragma unroll
            for (int i = 0; i < 16; ++i) {
              const int qr = (i & 3) + 8 * (i >> 2) + 4 * hi;
              const float cr = __shfl(corr, qr);
              acc0[i] *= cr; acc1[i] *= cr;
            }
            l_st *= corr;
            m_st = m_new;
          }

          float ls = 0.f;
#pragma unroll
          for (int r = 0; r < 16; ++r) { p[r] = __expf(p[r] - m_st); ls += p[r]; }
          ls += __shfl_xor(ls, 32);
          l_st += ls;

#pragma unroll
          for (int ks = 0; ks < 2; ++ks) {
            const int bb = ks * 8;
            float u[4];
#pragma unroll
            for (int i = 0; i < 4; ++i) {
              const float tv = hi ? p[bb + i] : p[bb + 4 + i];
              u[i] = __shfl_xor(tv, 32);
            }
            bf16x8 pa;
#pragma unroll
            for (int j = 0; j < 4; ++j) {
              pa[j]     = (short)f2bf(hi ? u[j] : p[bb + j]);
              pa[4 + j] = (short)f2bf(hi ? p[bb + 4 + j] : u[j]);
            }
            const int ch = ss * 4 + ks * 2 + hi;
            const bf16x8 bv0 = *reinterpret_cast<const bf16x8*>(
                &Vl[cur][l31 * 64 + (ch ^ swz) * 8]);
            const bf16x8 bv1 = *reinterpret_cast<const bf16x8*>(
                &Vl[cur][(32 + l31) * 64 + (ch ^ swz) * 8]);
            acc0 = mfma32x32x16(pa, bv0, acc0);
            acc1 = mfma32x32x16(pa, bv1, acc1);
          }
        }
      }
      __syncthreads();
      cur ^= 1;
    }

    const float invl = 1.0f / l_st;
#pragma unroll
    for (int r = 0; r < 16; ++r) {
      const int qr = (r & 3) + 8 * (r >> 2) + 4 * hi;
      const float il = __shfl(invl, qr);
      unsigned short* Orow = O + baseQ + (size_t)(qw + qr) * DM;
      Orow[l31]      = f2bf(acc0[r] * il);
      Orow[32 + l31] = f2bf(acc1[r] * il);
    }
  }
}

// ---------- launch ----------
extern "C" void kernel_launch(void* const* d_in, const int* in_sizes, int n_in,
                              void* d_out, int out_size, void* d_ws, size_t ws_size,
                              hipStream_t stream) {
  (void)in_sizes; (void)n_in; (void)out_size; (void)ws_size;
  constexpr int Bx = 4, S = 2048, DM = 1024;
  constexpr int M = Bx * S;          // 8192
  constexpr size_t XEL = (size_t)M * DM;       // 8388608

  const float* Wq = (const float*)d_in[1];
  const float* Wk = (const float*)d_in[2];
  const float* Wv = (const float*)d_in[3];
  const float* Wo = (const float*)d_in[4];
  const float* Xf = (const float*)d_in[5];
  float* out = (float*)d_out;

  char* ws = (char*)d_ws;
  unsigned short* Xbf = (unsigned short*)(ws + 0);           // 16 MB (reused as attn-out)
  unsigned short* Qb  = (unsigned short*)(ws + 16777216);    // [8192][1024]
  unsigned short* Kb  = (unsigned short*)(ws + 33554432);    // [8192][1056] padded
  unsigned short* Vtb = (unsigned short*)(ws + 50855936);    // [4096][2080] padded V^T
  unsigned short* Wfb = (unsigned short*)(ws + 67895296);    // [3072][1024] Wq|Wk|Wv fused
  unsigned short* Wob = (unsigned short*)(ws + 74186752);    // [1024][1024]
  unsigned short* Ob  = Xbf;   // alias: X dead after QKV projection

  // 1) convert inputs to bf16 (2 launches)
  cvt_f32_bf16<<<(int)(XEL / 1024), 256, 0, stream>>>(Xf, Xbf, (int)XEL);
  cvt_w4<<<4096, 256, 0, stream>>>(Wq, Wk, Wv, Wo, Wfb);   // Wo lands at Wfb+3M = Wob

  // 2) fused QKV projection: grid (3072/128, 8192/64/2) = (24, 64), 1536 blocks
  dim3 gq(3072 / 128, M / 128);
  gemm_qkv<<<gq, 256, 0, stream>>>(Xbf, Wfb, Qb, Kb, Vtb);

  // 3) causal flash attention: 512 blocks, uniform work via {pr, 15-pr} pairing
  attn_fwd<<<Bx * 16 * 8, 256, 0, stream>>>(Qb, Kb, Vtb, Ob);

  // 4) output projection (f32 out)
  dim3 gg(DM / 128, M / 128);
  gemm_op<<<gg, 256, 0, stream>>>(Ob, Wob, out);
}